// Round 7
// baseline (172.574 us; speedup 1.0000x reference)
//
#include <hip/hip_runtime.h>
#include <hip/hip_bf16.h>

typedef __attribute__((ext_vector_type(8))) short short8;
typedef __attribute__((ext_vector_type(4))) float f32x4;

#define REP 8   // DIAGNOSTIC: repeat K1 body 8x (idempotent) so its dispatch
                // exceeds the ~40us harness fills and appears in rocprof top-5.

// bf16 truncation (round-toward-zero). Safe: s = ||z3||^2 cancels exactly in
// out = s*d / max(s*sqrt(n1*n2), eps); only d,n1,n2 (pure f32) reach out.
__device__ __forceinline__ unsigned int bfhi(float f) {
    return __builtin_bit_cast(unsigned int, f);
}
__device__ __forceinline__ unsigned int pack2(float lo, float hi) {
    return (bfhi(lo) >> 16) | (bfhi(hi) & 0xffff0000u);
}
__device__ __forceinline__ short8 pack_bf8(float4 a, float4 b) {
    uint4 u;
    u.x = pack2(a.x, a.y);
    u.y = pack2(a.z, a.w);
    u.z = pack2(b.x, b.y);
    u.w = pack2(b.z, b.w);
    return __builtin_bit_cast(short8, u);
}

// K1: heterogeneous, NO cross-block sync. 576 blocks x 512 threads.
//   bid 0..63   (Q): 64 rows. 3 K-tiles: stage Xq f32->bf16 LDS; GEMM1 with
//                    W1 f32 packed in-register (wave w owns 16 cols); GEMM2/3
//                    likewise; s = ||z3||^2 -> ws.
//   bid 64..575 (P): 8 rows (wave w = row w): stream Xp1/Xp2, butterfly
//                    reduce -> d, n1, n2 -> ws.
// ws layout (f32): d@0, n1@4096, n2@8192, s@12288.
__global__ __launch_bounds__(512, 4) void pq_kernel(
    const float* __restrict__ X,
    const float* __restrict__ W1, const float* __restrict__ b1,
    const float* __restrict__ W2, const float* __restrict__ b2,
    const float* __restrict__ W3, const float* __restrict__ b3,
    float* __restrict__ wsf)
{
    __shared__ __align__(16) unsigned short xq[64][264];  // 64x256 bf16 K-tile
    __shared__ __align__(16) unsigned short z1[64][136];  // 64x128 bf16
    __shared__ __align__(16) unsigned short z2[64][72];   // 64x64  bf16
    __shared__ float sred[2][64];

    const int tid  = threadIdx.x;
    const int wid  = tid >> 6;
    const int lane = tid & 63;
    const int l15  = lane & 15;
    const int l4   = lane >> 4;
    const int bid  = blockIdx.x;

    for (int rep = 0; rep < REP; ++rep) {
        if (bid < 64) {
            // ================= Q path =================
            const int row0 = bid * 64;

            // ---- GEMM1: z1 = relu(Xq @ W1^T + b1), M=64, N=128, K=768 ----
            f32x4 acc[4] = {{0,0,0,0},{0,0,0,0},{0,0,0,0},{0,0,0,0}};
            const float* bp = W1 + (size_t)(16 * wid + l15) * 768 + l4 * 8;
            for (int kt = 0; kt < 3; ++kt) {
                // stage 64 rows x 256 cols f32 -> bf16 LDS (issue all loads first)
                float4 v[8];
#pragma unroll
                for (int m = 0; m < 8; ++m) {
                    int i = tid + 512 * m;           // 0..4095
                    int r = i >> 6, c4 = i & 63;
                    v[m] = *(const float4*)(X + (size_t)(row0 + r) * 2304 + kt * 256 + c4 * 4);
                }
#pragma unroll
                for (int m = 0; m < 8; ++m) {
                    int i = tid + 512 * m;
                    int r = i >> 6, c4 = i & 63;
                    uint2 qb;
                    qb.x = pack2(v[m].x, v[m].y);
                    qb.y = pack2(v[m].z, v[m].w);
                    *(uint2*)&xq[r][c4 * 4] = qb;
                }
                __syncthreads();
#pragma unroll
                for (int k0 = 0; k0 < 256; k0 += 32) {
                    float4 w0 = *(const float4*)(bp + kt * 256 + k0);
                    float4 w1 = *(const float4*)(bp + kt * 256 + k0 + 4);
                    short8 b = pack_bf8(w0, w1);
#pragma unroll
                    for (int m = 0; m < 4; ++m) {
                        short8 a = *(const short8*)&xq[16 * m + l15][k0 + l4 * 8];
                        acc[m] = __builtin_amdgcn_mfma_f32_16x16x32_bf16(a, b, acc[m], 0, 0, 0);
                    }
                }
                __syncthreads();  // before next stage overwrites xq
            }
            {
                float bv = b1[16 * wid + l15];
#pragma unroll
                for (int m = 0; m < 4; ++m)
#pragma unroll
                    for (int r = 0; r < 4; ++r) {
                        float vv = fmaxf(acc[m][r] + bv, 0.f);
                        z1[16 * m + 4 * l4 + r][16 * wid + l15] = (unsigned short)(bfhi(vv) >> 16);
                    }
            }
            __syncthreads();

            // ---- GEMM2: z2 = relu(z1 @ W2^T + b2), M=64, N=64, K=128 ----
            {
                const int ms = wid & 3, nh = wid >> 2;
                f32x4 a2[2] = {{0,0,0,0},{0,0,0,0}};
                const float* w2p0 = W2 + (size_t)(32 * nh + l15) * 128 + l4 * 8;
                const float* w2p1 = W2 + (size_t)(32 * nh + 16 + l15) * 128 + l4 * 8;
#pragma unroll
                for (int k0 = 0; k0 < 128; k0 += 32) {
                    short8 a  = *(const short8*)&z1[16 * ms + l15][k0 + l4 * 8];
                    short8 w0 = pack_bf8(*(const float4*)(w2p0 + k0), *(const float4*)(w2p0 + k0 + 4));
                    short8 w1 = pack_bf8(*(const float4*)(w2p1 + k0), *(const float4*)(w2p1 + k0 + 4));
                    a2[0] = __builtin_amdgcn_mfma_f32_16x16x32_bf16(a, w0, a2[0], 0, 0, 0);
                    a2[1] = __builtin_amdgcn_mfma_f32_16x16x32_bf16(a, w1, a2[1], 0, 0, 0);
                }
                float bv0 = b2[32 * nh + l15], bv1 = b2[32 * nh + 16 + l15];
#pragma unroll
                for (int r = 0; r < 4; ++r) {
                    float v0 = fmaxf(a2[0][r] + bv0, 0.f);
                    float v1 = fmaxf(a2[1][r] + bv1, 0.f);
                    z2[16 * ms + 4 * l4 + r][32 * nh + l15]      = (unsigned short)(bfhi(v0) >> 16);
                    z2[16 * ms + 4 * l4 + r][32 * nh + 16 + l15] = (unsigned short)(bfhi(v1) >> 16);
                }
            }
            __syncthreads();

            // ---- GEMM3: z3 = relu(z2 @ W3^T + b3), M=64, N=32, K=64; s=||z3||^2 ----
            {
                const int ms = wid & 3, gg = wid >> 2;   // gg in {0,1}
                f32x4 a3 = {0, 0, 0, 0};
                const float* w3p = W3 + (size_t)(16 * gg + l15) * 64 + l4 * 8;
#pragma unroll
                for (int k0 = 0; k0 < 64; k0 += 32) {
                    short8 a = *(const short8*)&z2[16 * ms + l15][k0 + l4 * 8];
                    short8 b = pack_bf8(*(const float4*)(w3p + k0), *(const float4*)(w3p + k0 + 4));
                    a3 = __builtin_amdgcn_mfma_f32_16x16x32_bf16(a, b, a3, 0, 0, 0);
                }
                float bv = b3[16 * gg + l15];
                float sv[4];
#pragma unroll
                for (int r = 0; r < 4; ++r) {
                    float vv = fmaxf(a3[r] + bv, 0.f);
                    sv[r] = vv * vv;
                }
#pragma unroll
                for (int m = 1; m < 16; m <<= 1)
#pragma unroll
                    for (int r = 0; r < 4; ++r) sv[r] += __shfl_xor(sv[r], m);
                if (l15 == 0)
#pragma unroll
                    for (int r = 0; r < 4; ++r) sred[gg][16 * ms + 4 * l4 + r] = sv[r];
            }
            __syncthreads();
            if (tid < 64) wsf[12288 + row0 + tid] = sred[0][tid] + sred[1][tid];
        } else {
            // ================= P path =================
            const int row = (bid - 64) * 8 + wid;
            const float* base = X + (size_t)row * 2304;
            float4 p1[3], p2[3];
#pragma unroll
            for (int m = 0; m < 3; ++m) p1[m] = *(const float4*)(base + 768 + (lane + 64 * m) * 4);
#pragma unroll
            for (int m = 0; m < 3; ++m) p2[m] = *(const float4*)(base + 1536 + (lane + 64 * m) * 4);
            float dd = 0.f, aa = 0.f, bb = 0.f;
#pragma unroll
            for (int m = 0; m < 3; ++m) {
                float4 x = p1[m], y = p2[m];
                dd += x.x * y.x + x.y * y.y + x.z * y.z + x.w * y.w;
                aa += x.x * x.x + x.y * x.y + x.z * x.z + x.w * x.w;
                bb += y.x * y.x + y.y * y.y + y.z * y.z + y.w * y.w;
            }
#pragma unroll
            for (int m = 1; m < 64; m <<= 1) {
                dd += __shfl_xor(dd, m);
                aa += __shfl_xor(aa, m);
                bb += __shfl_xor(bb, m);
            }
            if (lane == 0) {
                wsf[row]        = dd;
                wsf[4096 + row] = aa;
                wsf[8192 + row] = bb;
            }
        }
    }
}

// K2: combine. out = s*d / max(s*sqrt(n1*n2), eps)
__global__ __launch_bounds__(512) void combine(
    const float* __restrict__ wsf, float* __restrict__ out)
{
    int i = blockIdx.x * 512 + threadIdx.x;
    float d  = wsf[i];
    float n1 = wsf[4096 + i];
    float n2 = wsf[8192 + i];
    float s  = wsf[12288 + i];
    out[i] = (s * d) / fmaxf(s * sqrtf(n1 * n2), 1e-8f);
}

extern "C" void kernel_launch(void* const* d_in, const int* in_sizes, int n_in,
                              void* d_out, int out_size, void* d_ws, size_t ws_size,
                              hipStream_t stream)
{
    (void)in_sizes; (void)n_in; (void)out_size; (void)ws_size;
    const float* X  = (const float*)d_in[0];
    const float* W1 = (const float*)d_in[1];
    const float* b1 = (const float*)d_in[2];
    const float* W2 = (const float*)d_in[3];
    const float* b2 = (const float*)d_in[4];
    const float* W3 = (const float*)d_in[5];
    const float* b3 = (const float*)d_in[6];

    float* wsf = (float*)d_ws;   // d@0, n1@4096, n2@8192, s@12288 (f32)

    pq_kernel<<<dim3(576), dim3(512), 0, stream>>>(X, W1, b1, W2, b2, W3, b3, wsf);
    combine<<<dim3(8), dim3(512), 0, stream>>>(wsf, (float*)d_out);
}

// Round 8
// 38.305 us; speedup vs baseline: 4.5052x; 4.5052x over previous
//
#include <hip/hip_runtime.h>
#include <hip/hip_bf16.h>

typedef __attribute__((ext_vector_type(8))) short short8;
typedef __attribute__((ext_vector_type(4))) float f32x4;

// bf16 truncation (round-toward-zero). Safe: s = ||z3||^2 cancels exactly in
// out = s*d / max(s*sqrt(n1*n2), eps); only d,n1,n2 (pure f32) reach out.
__device__ __forceinline__ unsigned int bfhi(float f) {
    return __builtin_bit_cast(unsigned int, f);
}
__device__ __forceinline__ unsigned int pack2(float lo, float hi) {
    return (bfhi(lo) >> 16) | (bfhi(hi) & 0xffff0000u);
}

// K0: convert W1/W2/W3 f32 -> bf16 into ws. 106 blocks x 256 thr x 4 elems.
// ushort layout: W1b @ 0 (98304), W2b @ 98304 (8192), W3b @ 106496 (2048).
__global__ __launch_bounds__(256) void cvt_weights(
    const float* __restrict__ W1, const float* __restrict__ W2,
    const float* __restrict__ W3, unsigned short* __restrict__ wsb)
{
    int i4 = (blockIdx.x * 256 + threadIdx.x) * 4;
    const float* src;
    int off;
    if (i4 < 98304)       { src = W1; off = 0; }
    else if (i4 < 106496) { src = W2; off = 98304; }
    else                  { src = W3; off = 106496; }
    float4 v = *(const float4*)(src + (i4 - off));
    uint2 u;
    u.x = pack2(v.x, v.y);
    u.y = pack2(v.z, v.w);
    *(uint2*)&wsb[i4] = u;
}

// K1: homogeneous-balanced. 1024 blocks x 512 threads (8 waves), ~24 waves/CU.
//   even bid (Q-job, qid=bid>>1, rows qid*8..+7): Xq -> LDS bf16 (XOR-swizzled,
//     conflict-free b128 reads), 3-layer MLP via MFMA with bf16 weights and
//     depth-2 B prefetch; s = ||z3||^2. M-tile rows 8..15 are garbage-but-safe
//     (MFMA D-rows depend only on the same A-row).
//   odd bid (P-job, pid=bid>>1, rows pid*8..+7): wave = row: stream Xp1/Xp2,
//     butterfly-reduce d, n1, n2.
// wsf (f32): d@0, n1@4096, n2@8192, s@12288. wsb (ushort) at wsf+16384.
__global__ __launch_bounds__(512, 6) void pq_kernel(
    const float* __restrict__ X,
    const unsigned short* __restrict__ wsb,
    const float* __restrict__ b1,
    const float* __restrict__ b2,
    const float* __restrict__ b3,
    float* __restrict__ wsf)
{
    __shared__ __align__(16) unsigned short xq[16][768];  // rows 8..15 uninit (safe)
    __shared__ __align__(16) unsigned short z1[16][136];
    __shared__ __align__(16) unsigned short z2[16][72];
    __shared__ float sred[2][16];

    const int tid  = threadIdx.x;
    const int wid  = tid >> 6;
    const int lane = tid & 63;
    const int l15  = lane & 15;
    const int l4   = lane >> 4;

    if (blockIdx.x & 1) {
        // ================= P path =================
        const int row = (blockIdx.x >> 1) * 8 + wid;
        const float* base = X + (size_t)row * 2304;
        float4 p1[3], p2[3];
#pragma unroll
        for (int m = 0; m < 3; ++m) p1[m] = *(const float4*)(base + 768 + (lane + 64 * m) * 4);
#pragma unroll
        for (int m = 0; m < 3; ++m) p2[m] = *(const float4*)(base + 1536 + (lane + 64 * m) * 4);
        float dd = 0.f, aa = 0.f, bb = 0.f;
#pragma unroll
        for (int m = 0; m < 3; ++m) {
            float4 x = p1[m], y = p2[m];
            dd += x.x * y.x + x.y * y.y + x.z * y.z + x.w * y.w;
            aa += x.x * x.x + x.y * x.y + x.z * x.z + x.w * x.w;
            bb += y.x * y.x + y.y * y.y + y.z * y.z + y.w * y.w;
        }
#pragma unroll
        for (int m = 1; m < 64; m <<= 1) {
            dd += __shfl_xor(dd, m);
            aa += __shfl_xor(aa, m);
            bb += __shfl_xor(bb, m);
        }
        if (lane == 0) {
            wsf[row]        = dd;
            wsf[4096 + row] = aa;
            wsf[8192 + row] = bb;
        }
        return;
    }

    // ================= Q path =================
    const int qid  = blockIdx.x >> 1;      // 0..511
    const int row0 = qid * 8;
    const unsigned short* W1b = wsb;
    const unsigned short* W2b = wsb + 98304;
    const unsigned short* W3b = wsb + 106496;

    // ---- stage: wave w = row w. 96 16B-chunks/row; lane does chunk `lane`
    //      (+ chunk 64+lane for lanes 0..31). XOR-swizzle bit 4..6 by row. ----
    {
        const float* rp = X + (size_t)(row0 + wid) * 2304;
        char* rowbase = (char*)&xq[wid][0];
        {
            float4 a = *(const float4*)(rp + lane * 8);
            float4 b = *(const float4*)(rp + lane * 8 + 4);
            uint4 u;
            u.x = pack2(a.x, a.y); u.y = pack2(a.z, a.w);
            u.z = pack2(b.x, b.y); u.w = pack2(b.z, b.w);
            *(uint4*)(rowbase + ((16 * lane) ^ ((wid & 7) << 4))) = u;
        }
        if (lane < 32) {
            int c = 64 + lane;
            float4 a = *(const float4*)(rp + c * 8);
            float4 b = *(const float4*)(rp + c * 8 + 4);
            uint4 u;
            u.x = pack2(a.x, a.y); u.y = pack2(a.z, a.w);
            u.z = pack2(b.x, b.y); u.w = pack2(b.z, b.w);
            *(uint4*)(rowbase + ((16 * c) ^ ((wid & 7) << 4)));
            *(uint4*)(rowbase + ((16 * c) ^ ((wid & 7) << 4))) = u;
        }
    }
    __syncthreads();

    // ---- GEMM1: z1 = relu(Xq @ W1^T + b1), M=16(8 real), N=128, K=768 ----
    // wave w: cols 16w..16w+15. a from swizzled LDS, b bf16 16B, depth-2 pipeline.
    {
        f32x4 acc = {0.f, 0.f, 0.f, 0.f};
        const unsigned short* bp = W1b + (size_t)(16 * wid + l15) * 768 + l4 * 8;
        const char* arow = (const char*)&xq[l15][0];
        const int aswz = (l15 & 7) << 4;
        short8 bcur = *(const short8*)(bp);
#pragma unroll
        for (int k0 = 0; k0 < 768; k0 += 32) {
            short8 bnext = (k0 < 736) ? *(const short8*)(bp + k0 + 32) : bcur;
            short8 a = *(const short8*)(arow + ((16 * (k0 / 8 + l4)) ^ aswz));
            acc = __builtin_amdgcn_mfma_f32_16x16x32_bf16(a, bcur, acc, 0, 0, 0);
            bcur = bnext;
        }
        float bv = b1[16 * wid + l15];
#pragma unroll
        for (int r = 0; r < 4; ++r) {
            float v = fmaxf(acc[r] + bv, 0.f);
            z1[4 * l4 + r][16 * wid + l15] = (unsigned short)(bfhi(v) >> 16);
        }
    }
    __syncthreads();

    // ---- GEMM2: z2 = relu(z1 @ W2^T + b2), M=16(8 real), N=64, K=128 ----
    if (wid < 4) {
        f32x4 acc = {0.f, 0.f, 0.f, 0.f};
        const unsigned short* bp = W2b + (16 * wid + l15) * 128 + l4 * 8;
#pragma unroll
        for (int ks = 0; ks < 4; ++ks) {
            short8 a = *(const short8*)&z1[l15][ks * 32 + l4 * 8];
            short8 b = *(const short8*)(bp + ks * 32);
            acc = __builtin_amdgcn_mfma_f32_16x16x32_bf16(a, b, acc, 0, 0, 0);
        }
        float bv = b2[16 * wid + l15];
#pragma unroll
        for (int r = 0; r < 4; ++r) {
            float v = fmaxf(acc[r] + bv, 0.f);
            z2[4 * l4 + r][16 * wid + l15] = (unsigned short)(bfhi(v) >> 16);
        }
    }
    __syncthreads();

    // ---- GEMM3: z3 = relu(z2 @ W3^T + b3), M=16(8 real), N=32, K=64; s ----
    if (wid < 2) {
        f32x4 acc = {0.f, 0.f, 0.f, 0.f};
        const unsigned short* bp = W3b + (16 * wid + l15) * 64 + l4 * 8;
#pragma unroll
        for (int ks = 0; ks < 2; ++ks) {
            short8 a = *(const short8*)&z2[l15][ks * 32 + l4 * 8];
            short8 b = *(const short8*)(bp + ks * 32);
            acc = __builtin_amdgcn_mfma_f32_16x16x32_bf16(a, b, acc, 0, 0, 0);
        }
        float bv = b3[16 * wid + l15];
        float sv[4];
#pragma unroll
        for (int r = 0; r < 4; ++r) {
            float v = fmaxf(acc[r] + bv, 0.f);
            sv[r] = v * v;
        }
#pragma unroll
        for (int m = 1; m < 16; m <<= 1)
#pragma unroll
            for (int r = 0; r < 4; ++r) sv[r] += __shfl_xor(sv[r], m);
        if (l15 == 0)
#pragma unroll
            for (int r = 0; r < 4; ++r) sred[wid][4 * l4 + r] = sv[r];
    }
    __syncthreads();
    if (tid < 8) wsf[12288 + row0 + tid] = sred[0][tid] + sred[1][tid];
}

// K2: combine. out = s*d / max(s*sqrt(n1*n2), eps)
__global__ __launch_bounds__(512) void combine(
    const float* __restrict__ wsf, float* __restrict__ out)
{
    int i = blockIdx.x * 512 + threadIdx.x;
    float d  = wsf[i];
    float n1 = wsf[4096 + i];
    float n2 = wsf[8192 + i];
    float s  = wsf[12288 + i];
    out[i] = (s * d) / fmaxf(s * sqrtf(n1 * n2), 1e-8f);
}

extern "C" void kernel_launch(void* const* d_in, const int* in_sizes, int n_in,
                              void* d_out, int out_size, void* d_ws, size_t ws_size,
                              hipStream_t stream)
{
    (void)in_sizes; (void)n_in; (void)out_size; (void)ws_size;
    const float* X  = (const float*)d_in[0];
    const float* W1 = (const float*)d_in[1];
    const float* b1 = (const float*)d_in[2];
    const float* W2 = (const float*)d_in[3];
    const float* b2 = (const float*)d_in[4];
    const float* W3 = (const float*)d_in[5];
    const float* b3 = (const float*)d_in[6];

    float* wsf          = (float*)d_ws;                   // d, n1, n2, s (4x4096)
    unsigned short* wsb = (unsigned short*)(wsf + 16384); // bf16 weights

    cvt_weights<<<dim3(106), dim3(256), 0, stream>>>(W1, W2, W3, wsb);
    pq_kernel<<<dim3(1024), dim3(512), 0, stream>>>(X, wsb, b1, b2, b3, wsf);
    combine<<<dim3(8), dim3(512), 0, stream>>>(wsf, (float*)d_out);
}

// Round 9
// 23.473 us; speedup vs baseline: 7.3521x; 1.6319x over previous
//
#include <hip/hip_runtime.h>
#include <hip/hip_bf16.h>

typedef __attribute__((ext_vector_type(8))) short short8;
typedef __attribute__((ext_vector_type(4))) float f32x4;

// bf16 truncation (round-toward-zero). Safe: s = ||z3||^2 cancels exactly in
// out = s*d / max(s*sqrt(n1*n2), eps); only d,n1,n2 (pure f32) reach out.
__device__ __forceinline__ unsigned int bfhi(float f) {
    return __builtin_bit_cast(unsigned int, f);
}
__device__ __forceinline__ unsigned int pack2(float lo, float hi) {
    return (bfhi(lo) >> 16) | (bfhi(hi) & 0xffff0000u);
}

// K0: convert W1/W2/W3 f32 -> bf16 into ws (vectorized x4).
// ushort layout: W1b @ 0 (98304), W2b @ 98304 (8192), W3b @ 106496 (2048).
__global__ __launch_bounds__(256) void cvt_weights(
    const float* __restrict__ W1, const float* __restrict__ W2,
    const float* __restrict__ W3, unsigned short* __restrict__ wsb)
{
    int i4 = (blockIdx.x * 256 + threadIdx.x) * 4;
    const float* src;
    int off;
    if (i4 < 98304)       { src = W1; off = 0; }
    else if (i4 < 106496) { src = W2; off = 98304; }
    else                  { src = W3; off = 106496; }
    float4 v = *(const float4*)(src + (i4 - off));
    uint2 u;
    u.x = pack2(v.x, v.y);
    u.y = pack2(v.z, v.w);
    *(uint2*)&wsb[i4] = u;
}

// K1: heterogeneous, concurrency-maximized. 768 blocks x 512 threads,
// launch_bounds(512,6) -> up to 3 blocks/CU (24 waves/CU); LDS ~31KB.
//   bid 0..255  (Q): 16 rows. ONE full-K stage (Xq -> LDS bf16, XOR-swizzled,
//                    6 float4/thread issued up-front), then GEMM1 as a single
//                    24-step loop (no intermediate barriers, depth-2 B
//                    prefetch, bf16 W1); GEMM2/3; s = ||z3||^2.
//   bid 256..767 (P): 8 rows (wave = row): 6 float4 issued up-front,
//                    butterfly-reduce d, n1, n2.
// wsf (f32): d@0, n1@4096, n2@8192, s@12288. wsb (ushort) at wsf+16384.
__global__ __launch_bounds__(512, 6) void pq_kernel(
    const float* __restrict__ X,
    const unsigned short* __restrict__ wsb,
    const float* __restrict__ b1,
    const float* __restrict__ b2,
    const float* __restrict__ b3,
    float* __restrict__ wsf)
{
    __shared__ __align__(16) char xq[16 * 1536];          // 16x768 bf16, XOR-swizzled
    __shared__ __align__(16) unsigned short z1[16][136];
    __shared__ __align__(16) unsigned short z2[16][72];
    __shared__ float sred[2][16];

    const int tid  = threadIdx.x;
    const int wid  = tid >> 6;
    const int lane = tid & 63;
    const int l15  = lane & 15;
    const int l4   = lane >> 4;

    if (blockIdx.x >= 256) {
        // ================= P path =================
        const int row = (int)(blockIdx.x - 256) * 8 + wid;
        const float* base = X + (size_t)row * 2304;
        float4 p1[3], p2[3];
#pragma unroll
        for (int m = 0; m < 3; ++m) p1[m] = *(const float4*)(base + 768 + (lane + 64 * m) * 4);
#pragma unroll
        for (int m = 0; m < 3; ++m) p2[m] = *(const float4*)(base + 1536 + (lane + 64 * m) * 4);
        float dd = 0.f, aa = 0.f, bb = 0.f;
#pragma unroll
        for (int m = 0; m < 3; ++m) {
            float4 x = p1[m], y = p2[m];
            dd += x.x * y.x + x.y * y.y + x.z * y.z + x.w * y.w;
            aa += x.x * x.x + x.y * x.y + x.z * x.z + x.w * x.w;
            bb += y.x * y.x + y.y * y.y + y.z * y.z + y.w * y.w;
        }
#pragma unroll
        for (int m = 1; m < 64; m <<= 1) {
            dd += __shfl_xor(dd, m);
            aa += __shfl_xor(aa, m);
            bb += __shfl_xor(bb, m);
        }
        if (lane == 0) {
            wsf[row]        = dd;
            wsf[4096 + row] = aa;
            wsf[8192 + row] = bb;
        }
        return;
    }

    // ================= Q path =================
    const int row0 = (int)blockIdx.x * 16;
    const unsigned short* W1b = wsb;
    const unsigned short* W2b = wsb + 98304;
    const unsigned short* W3b = wsb + 106496;

    // ---- stage: 16 rows x 96 16B-chunks = 1536 chunks / 512 thr = 3 each.
    //      All 6 global float4 issued before any use. XOR-swizzle by row. ----
    {
        float4 v[6];
        int rows[3], ccs[3];
#pragma unroll
        for (int j = 0; j < 3; ++j) {
            int ci = tid + 512 * j;            // 0..1535
            rows[j] = ci >> 6 >> 0;            // placeholder, fixed below
        }
#pragma unroll
        for (int j = 0; j < 3; ++j) {
            int ci = tid + 512 * j;
            int r  = ci / 96;
            int cc = ci - r * 96;
            rows[j] = r; ccs[j] = cc;
            const float* p = X + (size_t)(row0 + r) * 2304 + cc * 8;
            v[2 * j]     = *(const float4*)(p);
            v[2 * j + 1] = *(const float4*)(p + 4);
        }
#pragma unroll
        for (int j = 0; j < 3; ++j) {
            uint4 u;
            u.x = pack2(v[2 * j].x,     v[2 * j].y);
            u.y = pack2(v[2 * j].z,     v[2 * j].w);
            u.z = pack2(v[2 * j + 1].x, v[2 * j + 1].y);
            u.w = pack2(v[2 * j + 1].z, v[2 * j + 1].w);
            int byteoff = (rows[j] * 1536 + ccs[j] * 16) ^ ((rows[j] & 7) << 4);
            *(uint4*)(xq + byteoff) = u;
        }
    }
    __syncthreads();

    // ---- GEMM1: z1 = relu(Xq @ W1^T + b1), M=16, N=128, K=768 ----
    // wave w: cols 16w..16w+15; single 24-step loop, depth-2 B prefetch.
    {
        f32x4 acc = {0.f, 0.f, 0.f, 0.f};
        const unsigned short* bp = W1b + (size_t)(16 * wid + l15) * 768 + l4 * 8;
        const int abase = l15 * 1536;
        const int aswz  = (l15 & 7) << 4;
        short8 bcur = *(const short8*)(bp);
#pragma unroll
        for (int k0 = 0; k0 < 768; k0 += 32) {
            short8 bnext = (k0 < 736) ? *(const short8*)(bp + k0 + 32) : bcur;
            short8 a = *(const short8*)(xq + ((abase + (k0 + l4 * 8) * 2) ^ aswz));
            acc = __builtin_amdgcn_mfma_f32_16x16x32_bf16(a, bcur, acc, 0, 0, 0);
            bcur = bnext;
        }
        float bv = b1[16 * wid + l15];
#pragma unroll
        for (int r = 0; r < 4; ++r) {
            float v = fmaxf(acc[r] + bv, 0.f);
            z1[4 * l4 + r][16 * wid + l15] = (unsigned short)(bfhi(v) >> 16);
        }
    }
    __syncthreads();

    // ---- GEMM2: z2 = relu(z1 @ W2^T + b2), M=16, N=64, K=128 (waves 0-3) ----
    if (wid < 4) {
        f32x4 acc = {0.f, 0.f, 0.f, 0.f};
        const unsigned short* bp = W2b + (16 * wid + l15) * 128 + l4 * 8;
#pragma unroll
        for (int ks = 0; ks < 4; ++ks) {
            short8 a = *(const short8*)&z1[l15][ks * 32 + l4 * 8];
            short8 b = *(const short8*)(bp + ks * 32);
            acc = __builtin_amdgcn_mfma_f32_16x16x32_bf16(a, b, acc, 0, 0, 0);
        }
        float bv = b2[16 * wid + l15];
#pragma unroll
        for (int r = 0; r < 4; ++r) {
            float v = fmaxf(acc[r] + bv, 0.f);
            z2[4 * l4 + r][16 * wid + l15] = (unsigned short)(bfhi(v) >> 16);
        }
    }
    __syncthreads();

    // ---- GEMM3: z3 = relu(z2 @ W3^T + b3), M=16, N=32, K=64 (waves 0-1); s ----
    if (wid < 2) {
        f32x4 acc = {0.f, 0.f, 0.f, 0.f};
        const unsigned short* bp = W3b + (16 * wid + l15) * 64 + l4 * 8;
#pragma unroll
        for (int ks = 0; ks < 2; ++ks) {
            short8 a = *(const short8*)&z2[l15][ks * 32 + l4 * 8];
            short8 b = *(const short8*)(bp + ks * 32);
            acc = __builtin_amdgcn_mfma_f32_16x16x32_bf16(a, b, acc, 0, 0, 0);
        }
        float bv = b3[16 * wid + l15];
        float sv[4];
#pragma unroll
        for (int r = 0; r < 4; ++r) {
            float v = fmaxf(acc[r] + bv, 0.f);
            sv[r] = v * v;
        }
#pragma unroll
        for (int m = 1; m < 16; m <<= 1)
#pragma unroll
            for (int r = 0; r < 4; ++r) sv[r] += __shfl_xor(sv[r], m);
        if (l15 == 0)
#pragma unroll
            for (int r = 0; r < 4; ++r) sred[wid][4 * l4 + r] = sv[r];
    }
    __syncthreads();
    if (tid < 16) wsf[12288 + row0 + tid] = sred[0][tid] + sred[1][tid];
}

// K2: combine. out = s*d / max(s*sqrt(n1*n2), eps)
__global__ __launch_bounds__(512) void combine(
    const float* __restrict__ wsf, float* __restrict__ out)
{
    int i = blockIdx.x * 512 + threadIdx.x;
    float d  = wsf[i];
    float n1 = wsf[4096 + i];
    float n2 = wsf[8192 + i];
    float s  = wsf[12288 + i];
    out[i] = (s * d) / fmaxf(s * sqrtf(n1 * n2), 1e-8f);
}

extern "C" void kernel_launch(void* const* d_in, const int* in_sizes, int n_in,
                              void* d_out, int out_size, void* d_ws, size_t ws_size,
                              hipStream_t stream)
{
    (void)in_sizes; (void)n_in; (void)out_size; (void)ws_size;
    const float* X  = (const float*)d_in[0];
    const float* W1 = (const float*)d_in[1];
    const float* b1 = (const float*)d_in[2];
    const float* W2 = (const float*)d_in[3];
    const float* b2 = (const float*)d_in[4];
    const float* W3 = (const float*)d_in[5];
    const float* b3 = (const float*)d_in[6];

    float* wsf          = (float*)d_ws;                   // d, n1, n2, s (4x4096)
    unsigned short* wsb = (unsigned short*)(wsf + 16384); // bf16 weights

    cvt_weights<<<dim3(106), dim3(256), 0, stream>>>(W1, W2, W3, wsb);
    pq_kernel<<<dim3(768), dim3(512), 0, stream>>>(X, wsb, b1, b2, b3, wsf);
    combine<<<dim3(8), dim3(512), 0, stream>>>(wsf, (float*)d_out);
}